// Round 5
// baseline (226.386 us; speedup 1.0000x reference)
//
#include <hip/hip_runtime.h>
#include <hip/hip_fp16.h>

// SoftPerspectiveShader: barycentric texture sampling + softmax RGB blend.
// N=4, H=W=512, K=8, F=200000.
//
// R1: gate face_colors gather on weight magnitude (zbuf sorted ->
//     exp((zinv-zmax)/1e-4) underflows unless within ~1.2e-3 of zmax).
// R2-R5: nt streams / deferred bary / 2px-per-thread — ALL NEUTRAL at
//     65-69 us, 2.7 TB/s, VALU 10-12%, FETCH ~160 MB. Occupancy 65%->39%
//     with no perf change => not latency-hiding-bound, not issue-bound.
// R6 (this round): the binding constraint is divergent line-fill
//     throughput: ~2 divergent 128B-line requests/pixel served at L2-MISS
//     latency (face_colors = 7.2 MB > 4 MB per-XCD L2 -> capacity thrash),
//     throughput capped at ~MSHR_depth/latency per CU. Fix the LATENCY:
//     repack face_colors to fp16 [F][10] (20 B/face, 4 MB) in workspace ->
//     fits per-XCD L2; nt streams protect it. Gather = dwordx4 + ushort,
//     mostly L2 hits. fp16 texel error ~5e-4 vs 0.02 tolerance.

#define KFRAG 8

typedef int   ivec4 __attribute__((ext_vector_type(4)));
typedef float fvec4 __attribute__((ext_vector_type(4)));
typedef float fvec4a __attribute__((ext_vector_type(4), aligned(4)));
typedef unsigned int uvec4a __attribute__((ext_vector_type(4), aligned(4)));

__device__ __forceinline__ float h2f(unsigned short u) {
    __half h;
    __builtin_memcpy(&h, &u, 2);
    return __half2float(h);
}

// ---- prepass: face_colors f32 [F][9] -> fp16 [F][10] in workspace ----
__global__ __launch_bounds__(256) void repack_kernel(
    const float* __restrict__ fc, __half* __restrict__ ht, int F9)
{
    int i = blockIdx.x * blockDim.x + threadIdx.x;
    if (i >= F9) return;
    int f = i / 9;
    int c = i - f * 9;
    ht[(size_t)f * 10 + c] = __float2half(fc[i]);
}

template <int USE_H>
__global__ __launch_bounds__(256) void soft_shader_kernel(
    const int*    __restrict__ p2f,         // [NP, 8]
    const float*  __restrict__ bary,        // [NP, 8, 3]
    const float*  __restrict__ zbuf,        // [NP, 8]
    const float*  __restrict__ dists,       // [NP, 8]
    const float*  __restrict__ face_colors, // [F, 3, 3] f32
    const __half* __restrict__ halfTab,     // [F, 10] fp16 (ws) or null
    float*        __restrict__ out,         // [NP, 4]
    int NP)
{
    constexpr float SIGMA_INV = 1.0f / 1e-4f;
    constexpr float GAMMA_INV = 1.0f / 1e-4f;
    constexpr float EPS    = 1e-10f;
    constexpr float ZNEAR  = 1.0f;
    constexpr float ZFAR   = 100.0f;
    constexpr float ZSCALE = 1.0f / (ZFAR - ZNEAR);
    constexpr float ZCUT = -1.2e-3f; // exp(ZCUT*1e4) < 1e-5: negligible weight

    int p = blockIdx.x * blockDim.x + threadIdx.x;
    if (p >= NP) return;

    // ---- nt streams (evict-first in L2/L3 -> protect the fp16 table) ----
    const ivec4* p2f4 = (const ivec4*)p2f + (size_t)p * 2;
    ivec4 f0 = __builtin_nontemporal_load(p2f4 + 0);
    ivec4 f1 = __builtin_nontemporal_load(p2f4 + 1);

    const fvec4* zb4 = (const fvec4*)zbuf + (size_t)p * 2;
    fvec4 z0 = __builtin_nontemporal_load(zb4 + 0);
    fvec4 z1 = __builtin_nontemporal_load(zb4 + 1);
    const fvec4* dd4 = (const fvec4*)dists + (size_t)p * 2;
    fvec4 d0 = __builtin_nontemporal_load(dd4 + 0);
    fvec4 d1 = __builtin_nontemporal_load(dd4 + 1);

    int fid[KFRAG] = {f0.x, f0.y, f0.z, f0.w, f1.x, f1.y, f1.z, f1.w};

    // winner = first valid fragment (sorted zbuf -> max zinv among valid)
    int fidw = -1, kw = 0;
#pragma unroll
    for (int k = KFRAG - 1; k >= 0; --k)
        if (fid[k] >= 0) { fidw = fid[k]; kw = k; }

    // ---- winner's gathers: bary dwordx4 (clamped) + fp16 colors ----
    float wb0 = 0.f, wb1 = 0.f, wb2 = 0.f;
    float fcv[9] = {0, 0, 0, 0, 0, 0, 0, 0, 0};
    if (fidw >= 0) {
        // 12 B of bary as one dwordx4; 4-B aligned (96p + 12kw). Clamp the
        // single case (p=NP-1, kw=7) that would read 4 B past the buffer.
        size_t boff = (size_t)p * 24 + kw * 3; // in floats
        bool cl = (boff + 4) > (size_t)NP * 24;
        const float* bb = bary + (boff - (cl ? 1 : 0));
        fvec4a bq = *(const fvec4a*)bb;
        wb0 = cl ? bq.y : bq.x;
        wb1 = cl ? bq.z : bq.y;
        wb2 = cl ? bq.w : bq.z;

        if (USE_H) {
            const __half* hp = halfTab + (size_t)fidw * 10; // 20 B/face, 4-aligned
            uvec4a q = *(const uvec4a*)hp;                  // h0..h7
            unsigned short h8 = ((const unsigned short*)hp)[8];
            unsigned int w0 = q.x, w1 = q.y, w2 = q.z, w3 = q.w;
            fcv[0] = h2f((unsigned short)(w0 & 0xffff));
            fcv[1] = h2f((unsigned short)(w0 >> 16));
            fcv[2] = h2f((unsigned short)(w1 & 0xffff));
            fcv[3] = h2f((unsigned short)(w1 >> 16));
            fcv[4] = h2f((unsigned short)(w2 & 0xffff));
            fcv[5] = h2f((unsigned short)(w2 >> 16));
            fcv[6] = h2f((unsigned short)(w3 & 0xffff));
            fcv[7] = h2f((unsigned short)(w3 >> 16));
            fcv[8] = h2f(h8);
        } else {
            __builtin_memcpy(fcv, face_colors + (size_t)fidw * 9, 36);
        }
    }

    // ---- gate math (overlaps the gather round-trip) ----
    float zb_[KFRAG] = {z0.x, z0.y, z0.z, z0.w, z1.x, z1.y, z1.z, z1.w};
    float dd_[KFRAG] = {d0.x, d0.y, d0.z, d0.w, d1.x, d1.y, d1.z, d1.w};

    float zinv[KFRAG], prob[KFRAG];
    float zmax = EPS;
    float keep = 1.0f; // prod(1 - prob) = 1 - alpha
#pragma unroll
    for (int k = 0; k < KFRAG; ++k) {
        bool v = (fid[k] >= 0);
        zinv[k] = v ? ((ZFAR - zb_[k]) * ZSCALE) : 0.0f;
        zmax = fmaxf(zmax, zinv[k]);
        prob[k] = v ? (1.0f / (1.0f + __expf(dd_[k] * SIGMA_INV))) : 0.0f;
        keep *= (1.0f - prob[k]);
    }

    float pw = 0.f, zw = 0.f;
#pragma unroll
    for (int k = KFRAG - 1; k >= 0; --k)
        if (fid[k] >= 0) { pw = prob[k]; zw = zinv[k]; }

    float delta = fmaxf(__expf((EPS - zmax) * GAMMA_INV), EPS);
    float denom = delta;
    float r = 0.f, g = 0.f, b = 0.f;

    if (fidw >= 0) {
        float w = pw * __expf((zw - zmax) * GAMMA_INV); // zw==zmax -> 1
        float tr = fmaf(wb0, fcv[0], fmaf(wb1, fcv[3], wb2 * fcv[6]));
        float tg = fmaf(wb0, fcv[1], fmaf(wb1, fcv[4], wb2 * fcv[7]));
        float tb = fmaf(wb0, fcv[2], fmaf(wb1, fcv[5], wb2 * fcv[8]));
        denom += w;
        r = fmaf(w, tr, r);
        g = fmaf(w, tg, g);
        b = fmaf(w, tb, b);
    }

    // rare extra gate-passers (~0.8%/pixel): execz-skipped, f32 path
#pragma unroll
    for (int k = 0; k < KFRAG; ++k) {
        if ((fid[k] >= 0) && (k != kw) && (zinv[k] - zmax > ZCUT)) {
            float w = prob[k] * __expf((zinv[k] - zmax) * GAMMA_INV);
            const float* bp = bary + (size_t)p * (KFRAG * 3) + k * 3;
            float c0 = bp[0], c1 = bp[1], c2 = bp[2];
            const float* fc = face_colors + (size_t)fid[k] * 9;
            float e[9];
            __builtin_memcpy(e, fc, 36);
            float tr = fmaf(c0, e[0], fmaf(c1, e[3], c2 * e[6]));
            float tg = fmaf(c0, e[1], fmaf(c1, e[4], c2 * e[7]));
            float tb = fmaf(c0, e[2], fmaf(c1, e[5], c2 * e[8]));
            denom += w;
            r = fmaf(w, tr, r);
            g = fmaf(w, tg, g);
            b = fmaf(w, tb, b);
        }
    }

    float inv = 1.0f / denom;
    fvec4 o;
    o.x = (r + delta) * inv; // background (1,1,1): + delta/denom
    o.y = (g + delta) * inv;
    o.z = (b + delta) * inv;
    o.w = keep;
    __builtin_nontemporal_store(o, (fvec4*)out + p);
}

extern "C" void kernel_launch(void* const* d_in, const int* in_sizes, int n_in,
                              void* d_out, int out_size, void* d_ws, size_t ws_size,
                              hipStream_t stream) {
    const int*   p2f         = (const int*)d_in[0];
    const float* bary        = (const float*)d_in[1];
    const float* zbuf        = (const float*)d_in[2];
    const float* dists       = (const float*)d_in[3];
    const float* face_colors = (const float*)d_in[4];
    float* out = (float*)d_out;

    int NP = in_sizes[0] / KFRAG;     // N*H*W pixels
    int F9 = in_sizes[4];             // F * 9 floats
    int F  = F9 / 9;
    size_t need = (size_t)F * 10 * sizeof(__half); // 4.0 MB

    int block = 256;
    int grid = (NP + block - 1) / block;

    if (d_ws && ws_size >= need) {
        __half* ht = (__half*)d_ws;
        int rgrid = (F9 + block - 1) / block;
        repack_kernel<<<rgrid, block, 0, stream>>>(face_colors, ht, F9);
        soft_shader_kernel<1><<<grid, block, 0, stream>>>(
            p2f, bary, zbuf, dists, face_colors, ht, out, NP);
    } else {
        soft_shader_kernel<0><<<grid, block, 0, stream>>>(
            p2f, bary, zbuf, dists, face_colors, nullptr, out, NP);
    }
}